// Round 1
// baseline (3387.819 us; speedup 1.0000x reference)
//
#include <hip/hip_runtime.h>
#include <math.h>

#define NPRED  25200
#define BATCH  16
#define NC     80
#define MAXDET 300
#define NDIM   87

#define PREP_TPB 256
#define NMS_TPB  1024
#define EPT      25   // ceil(NPRED / NMS_TPB)

// ---------------------------------------------------------------------------
// Prep: per-box conf/cls/box/validity. All ops forced to unfused rn to match
// numpy fp32 bit-exactly (selection decisions depend on exact values).
// ---------------------------------------------------------------------------
__global__ __launch_bounds__(PREP_TPB)
void prep_kernel(const float* __restrict__ pred,
                 float* __restrict__ sc,
                 float4* __restrict__ box,
                 float4* __restrict__ info) {
    int gid = blockIdx.x * PREP_TPB + threadIdx.x;
    if (gid >= BATCH * NPRED) return;
    const float* p = pred + (size_t)gid * (NC + 5);
    float x = p[0], y = p[1], w = p[2], h = p[3], obj = p[4];
    float best = -INFINITY; int bc = 0;
    #pragma unroll 8
    for (int c = 0; c < NC; ++c) {
        float v = __fmul_rn(p[5 + c], obj);
        if (v > best) { best = v; bc = c; }   // strict > keeps first index on ties
    }
    float hw = __fmul_rn(w, 0.5f), hh = __fmul_rn(h, 0.5f);
    float x1 = __fsub_rn(x, hw), y1 = __fsub_rn(y, hh);
    float x2 = __fadd_rn(x, hw), y2 = __fadd_rn(y, hh);
    bool valid = (obj > 0.25f) && (best > 0.25f);
    sc[gid]   = valid ? best : -INFINITY;
    box[gid]  = make_float4(x1, y1, x2, y2);
    info[gid] = make_float4(best, (float)bc, obj, 0.0f);
}

// ---------------------------------------------------------------------------
// NMS: one block per image. Scores resident in VGPRs (25 per thread).
// 300 iterations of block-wide argmax (first-index tiebreak, matching
// jnp.argmax) followed by IoU suppression against the selected box.
// ---------------------------------------------------------------------------
__global__ __launch_bounds__(NMS_TPB)
void nms_kernel(const float* __restrict__ sc_g,
                const float4* __restrict__ box_g,
                const float4* __restrict__ info_g,
                const float* __restrict__ logits,
                float* __restrict__ out) {
    __shared__ float s_wval[NMS_TPB / 64];
    __shared__ int   s_widx[NMS_TPB / 64];
    __shared__ float s_b[9];   // x1,y1,x2,y2,area,conf,cls,obj,bestval
    __shared__ int   s_bi;

    const int img = blockIdx.x;
    const int t   = threadIdx.x;
    const float*  sc_img  = sc_g  + (size_t)img * NPRED;
    const float4* box_img = box_g + (size_t)img * NPRED;

    float sc[EPT];
    #pragma unroll
    for (int i = 0; i < EPT; ++i) {
        int e = t + i * NMS_TPB;
        sc[i] = (e < NPRED) ? sc_img[e] : -INFINITY;
    }

    for (int it = 0; it < MAXDET; ++it) {
        // ---- local argmax (ascending e, ties keep smaller index) ----
        float bv = -INFINITY; int bi = 0x7FFFFFFF;
        #pragma unroll
        for (int i = 0; i < EPT; ++i) {
            int e = t + i * NMS_TPB;
            float v = sc[i];
            if (v > bv || (v == bv && e < bi)) { bv = v; bi = e; }
        }
        // ---- wave (64-lane) reduce ----
        #pragma unroll
        for (int off = 32; off > 0; off >>= 1) {
            float ov = __shfl_down(bv, off);
            int   oi = __shfl_down(bi, off);
            if (ov > bv || (ov == bv && oi < bi)) { bv = ov; bi = oi; }
        }
        if ((t & 63) == 0) { s_wval[t >> 6] = bv; s_widx[t >> 6] = bi; }
        __syncthreads();
        // ---- cross-wave reduce in wave 0 ----
        if (t < 64) {
            bv = (t < NMS_TPB / 64) ? s_wval[t] : -INFINITY;
            bi = (t < NMS_TPB / 64) ? s_widx[t] : 0x7FFFFFFF;
            #pragma unroll
            for (int off = 8; off > 0; off >>= 1) {
                float ov = __shfl_down(bv, off);
                int   oi = __shfl_down(bi, off);
                if (ov > bv || (ov == bv && oi < bi)) { bv = ov; bi = oi; }
            }
            if (t == 0) {
                s_bi = bi;
                float4 b = box_img[bi];
                float area = __fmul_rn(__fsub_rn(b.z, b.x), __fsub_rn(b.w, b.y));
                float4 nf = info_g[(size_t)img * NPRED + bi];
                s_b[0] = b.x; s_b[1] = b.y; s_b[2] = b.z; s_b[3] = b.w;
                s_b[4] = area; s_b[5] = nf.x; s_b[6] = nf.y; s_b[7] = nf.z;
                s_b[8] = bv;
            }
        }
        __syncthreads();
        if (s_b[8] == -INFINITY) break;   // exhausted: remaining rows stay zero
        const int   idx   = s_bi;
        const float bx1 = s_b[0], by1 = s_b[1], bx2 = s_b[2], by2 = s_b[3];
        const float barea = s_b[4];

        // ---- emit the detection row (87 floats) ----
        if (t < NDIM) {
            float* o = out + ((size_t)img * MAXDET + it) * NDIM;
            float v;
            if (t < 4)       v = s_b[t];
            else if (t == 4) v = s_b[5];
            else if (t == 5) v = s_b[6];
            else if (t == 6) v = s_b[7];
            else             v = logits[((size_t)img * NPRED + idx) * NC + (t - 7)];
            o[t] = v;
        }

        // ---- suppression (selected box suppresses itself via IoU ~ 1) ----
        #pragma unroll
        for (int i = 0; i < EPT; ++i) {
            if (sc[i] != -INFINITY) {
                int e = t + i * NMS_TPB;
                float4 b = box_img[e];
                float lx = fmaxf(bx1, b.x), ly = fmaxf(by1, b.y);
                float rx = fminf(bx2, b.z), ry = fminf(by2, b.w);
                float ww = fmaxf(__fsub_rn(rx, lx), 0.0f);
                float hh = fmaxf(__fsub_rn(ry, ly), 0.0f);
                float inter = __fmul_rn(ww, hh);
                float a  = __fmul_rn(__fsub_rn(b.z, b.x), __fsub_rn(b.w, b.y));
                float denom = __fadd_rn(__fsub_rn(__fadd_rn(barea, a), inter), 1e-9f);
                float iou = __fdiv_rn(inter, denom);
                if (iou > 0.45f) sc[i] = -INFINITY;
            }
        }
        // no trailing sync needed: next-iter shared writes are fenced by the
        // two syncs above before any thread can reach them again
    }
}

extern "C" void kernel_launch(void* const* d_in, const int* in_sizes, int n_in,
                              void* d_out, int out_size, void* d_ws, size_t ws_size,
                              hipStream_t stream) {
    const float* pred   = (const float*)d_in[0];
    const float* logits = (const float*)d_in[1];
    float* out = (float*)d_out;

    char* ws = (char*)d_ws;
    float*  sc   = (float*)ws;                                                  // BATCH*NPRED f32
    float4* box  = (float4*)(ws + (size_t)BATCH * NPRED * sizeof(float));       // BATCH*NPRED f4
    float4* info = (float4*)(ws + (size_t)BATCH * NPRED * (sizeof(float) + sizeof(float4)));

    hipMemsetAsync(d_out, 0, (size_t)out_size * sizeof(float), stream);

    int total = BATCH * NPRED;
    prep_kernel<<<(total + PREP_TPB - 1) / PREP_TPB, PREP_TPB, 0, stream>>>(pred, sc, box, info);
    nms_kernel<<<BATCH, NMS_TPB, 0, stream>>>(sc, box, info, logits, out);
}

// Round 2
// 2662.013 us; speedup vs baseline: 1.2727x; 1.2727x over previous
//
#include <hip/hip_runtime.h>
#include <math.h>

#define NPRED  25200
#define BATCH  16
#define NC     80
#define MAXDET 300
#define NDIM   87

// ---------------------------------------------------------------------------
// Prep: LDS-staged coalesced loads (rows are 340 B; direct per-thread row
// reads over-fetch 4x). 128 boxes/block staged by 256 threads.
// All arithmetic unfused-rn to match numpy fp32 bit-exactly.
// ---------------------------------------------------------------------------
#define PREP_TPB 256
#define PB 128

__global__ __launch_bounds__(PREP_TPB)
void prep_kernel(const float* __restrict__ pred,
                 float* __restrict__ sc,
                 float4* __restrict__ box) {
    __shared__ float4 s4[PB * 85 / 4];
    float* s = (float*)s4;
    const int t = threadIdx.x;
    const float4* p4 = (const float4*)(pred + (size_t)blockIdx.x * (PB * 85));
    for (int i = t; i < PB * 85 / 4; i += PREP_TPB) s4[i] = p4[i];
    __syncthreads();
    if (t < PB) {
        const float* row = s + t * 85;
        float x = row[0], y = row[1], w = row[2], h = row[3], obj = row[4];
        float best = -INFINITY;
        #pragma unroll 8
        for (int c = 0; c < NC; ++c) {
            float v = __fmul_rn(row[5 + c], obj);
            if (v > best) best = v;          // strict >: first index on ties
        }
        float hw = __fmul_rn(w, 0.5f), hh = __fmul_rn(h, 0.5f);
        bool valid = (obj > 0.25f) && (best > 0.25f);
        int g = blockIdx.x * PB + t;
        sc[g]  = valid ? best : -INFINITY;
        box[g] = make_float4(__fsub_rn(x, hw), __fsub_rn(y, hh),
                             __fadd_rn(x, hw), __fadd_rn(y, hh));
    }
}

// ---------------------------------------------------------------------------
// NMS: one block per image, fully register-resident. 512 threads x 50
// elements: scores + boxes in VGPRs (2 waves/SIMD -> 256-reg budget).
// Suppression is pure predicated VALU — no memory on the critical path.
// Single barrier per iteration (parity-double-buffered leader slots; every
// thread redundantly reduces the 8 leaders).
// IoU test: fdiv_rn(inter,denom) > 0.45f  <=>  inter > K*denom exactly,
// K = (double)0.45f + 2^-26 (0.45f mantissa even => midpoint rounds down;
// 25-bit x 24-bit f64 product is exact), so selection is bit-identical.
// ---------------------------------------------------------------------------
#define TPB 512
#define EPT 50   // 512*50 = 25600 >= 25200
#define NWAVE (TPB / 64)

__global__ __launch_bounds__(TPB)
void nms_kernel(const float* __restrict__ sc_g,
                const float4* __restrict__ box_g,
                int* __restrict__ selidx,
                int* __restrict__ selcnt) {
    __shared__ float s_v[2][NWAVE];
    __shared__ int   s_i[2][NWAVE];
    const int img = blockIdx.x, t = threadIdx.x;
    const float*  sci = sc_g  + (size_t)img * NPRED;
    const float4* bxi = box_g + (size_t)img * NPRED;

    float sc[EPT], x1[EPT], y1[EPT], x2[EPT], y2[EPT];
    #pragma unroll
    for (int i = 0; i < EPT; ++i) {
        int e = t + i * TPB;
        if (e < NPRED) {
            sc[i] = sci[e];
            float4 b = bxi[e];
            x1[i] = b.x; y1[i] = b.y; x2[i] = b.z; y2[i] = b.w;
        } else {
            sc[i] = -INFINITY; x1[i] = y1[i] = x2[i] = y2[i] = 0.0f;
        }
    }
    const double K = (double)0.45f + 0x1p-26;

    int n = 0;
    for (int it = 0; it < MAXDET; ++it) {
        // local argmax (ascending e; strict > keeps first index on ties)
        float bv = -INFINITY; int bi = 0x7FFFFFFF;
        #pragma unroll
        for (int i = 0; i < EPT; ++i)
            if (sc[i] > bv) { bv = sc[i]; bi = t + i * TPB; }
        // wave reduce
        #pragma unroll
        for (int off = 32; off > 0; off >>= 1) {
            float ov = __shfl_down(bv, off);
            int   oi = __shfl_down(bi, off);
            if (ov > bv || (ov == bv && oi < bi)) { bv = ov; bi = oi; }
        }
        const int par = it & 1;
        if ((t & 63) == 0) { s_v[par][t >> 6] = bv; s_i[par][t >> 6] = bi; }
        __syncthreads();
        // every thread reduces the 8 leader pairs (broadcast LDS reads) —
        // result is uniform, so no second barrier and a uniform break.
        bv = s_v[par][0]; bi = s_i[par][0];
        #pragma unroll
        for (int w = 1; w < NWAVE; ++w) {
            float ov = s_v[par][w]; int oi = s_i[par][w];
            if (ov > bv || (ov == bv && oi < bi)) { bv = ov; bi = oi; }
        }
        if (bv == -INFINITY) break;
        if (t == 0) selidx[img * MAXDET + it] = bi;
        n = it + 1;

        float4 B = bxi[bi];   // lane-uniform broadcast load (L2)
        float barea = __fmul_rn(__fsub_rn(B.z, B.x), __fsub_rn(B.w, B.y));

        // suppression: pure in-register VALU (selected box self-suppresses
        // via IoU~1, matching the reference's where())
        #pragma unroll
        for (int i = 0; i < EPT; ++i) {
            float lx = fmaxf(B.x, x1[i]), ly = fmaxf(B.y, y1[i]);
            float rx = fminf(B.z, x2[i]), ry = fminf(B.w, y2[i]);
            float ww  = fmaxf(__fsub_rn(rx, lx), 0.0f);
            float hh2 = fmaxf(__fsub_rn(ry, ly), 0.0f);
            float inter = __fmul_rn(ww, hh2);
            float a = __fmul_rn(__fsub_rn(x2[i], x1[i]), __fsub_rn(y2[i], y1[i]));
            float denom = __fadd_rn(__fsub_rn(__fadd_rn(barea, a), inter), 1e-9f);
            if ((double)inter > K * (double)denom) sc[i] = -INFINITY;
        }
    }
    if (t == 0) selcnt[img] = n;
}

// ---------------------------------------------------------------------------
// Gather: writes every output element (zeros for padding rows — no memset
// needed). conf/cls/obj recomputed from pred with the identical rn ops.
// ---------------------------------------------------------------------------
#define GT 256

__global__ __launch_bounds__(GT)
void gather_kernel(const float* __restrict__ pred,
                   const float4* __restrict__ box,
                   const float* __restrict__ logits,
                   const int* __restrict__ selidx,
                   const int* __restrict__ selcnt,
                   float* __restrict__ out) {
    int tid = blockIdx.x * GT + threadIdx.x;
    if (tid >= BATCH * MAXDET * NDIM) return;
    int row = tid / NDIM, col = tid - row * NDIM;
    int img = row / MAXDET, det = row - img * MAXDET;
    float v = 0.0f;
    if (det < selcnt[img]) {
        int s = selidx[img * MAXDET + det];
        size_t g = (size_t)img * NPRED + s;
        if (col < 4) {
            float4 b = box[g];
            v = (col == 0) ? b.x : (col == 1) ? b.y : (col == 2) ? b.z : b.w;
        } else if (col == 6) {
            v = pred[g * 85 + 4];
        } else if (col >= 7) {
            v = logits[g * NC + (col - 7)];
        } else {
            const float* p = pred + g * 85;
            float obj = p[4];
            float best = -INFINITY; int bc = 0;
            #pragma unroll 8
            for (int c = 0; c < NC; ++c) {
                float q = __fmul_rn(p[5 + c], obj);
                if (q > best) { best = q; bc = c; }
            }
            v = (col == 4) ? best : (float)bc;
        }
    }
    out[tid] = v;
}

extern "C" void kernel_launch(void* const* d_in, const int* in_sizes, int n_in,
                              void* d_out, int out_size, void* d_ws, size_t ws_size,
                              hipStream_t stream) {
    const float* pred   = (const float*)d_in[0];
    const float* logits = (const float*)d_in[1];
    float* out = (float*)d_out;

    char* ws = (char*)d_ws;
    float*  sc     = (float*)ws;                                   // 1,612,800 B
    float4* box    = (float4*)(ws + 1612800);                      // 6,451,200 B
    int*    selidx = (int*)(ws + 1612800 + 6451200);               //    19,200 B
    int*    selcnt = (int*)(ws + 1612800 + 6451200 + 19200);       //        64 B

    prep_kernel<<<BATCH * NPRED / PB, PREP_TPB, 0, stream>>>(pred, sc, box);
    nms_kernel<<<BATCH, TPB, 0, stream>>>(sc, box, selidx, selcnt);
    int gtot = BATCH * MAXDET * NDIM;
    gather_kernel<<<(gtot + GT - 1) / GT, GT, 0, stream>>>(pred, box, logits, selidx, selcnt, out);
}

// Round 3
// 2327.928 us; speedup vs baseline: 1.4553x; 1.1435x over previous
//
#include <hip/hip_runtime.h>
#include <math.h>

#define NPRED  25200
#define BATCH  16
#define NC     80
#define MAXDET 300
#define NDIM   87

// ---------------------------------------------------------------------------
// Prep: LDS-staged coalesced loads (rows are 340 B; direct per-thread row
// reads over-fetch 4x). 128 boxes/block staged by 256 threads.
// All arithmetic unfused-rn to match numpy fp32 bit-exactly.
// ---------------------------------------------------------------------------
#define PREP_TPB 256
#define PB 128

__global__ __launch_bounds__(PREP_TPB)
void prep_kernel(const float* __restrict__ pred,
                 float* __restrict__ sc,
                 float4* __restrict__ box) {
    __shared__ float4 s4[PB * 85 / 4];
    float* s = (float*)s4;
    const int t = threadIdx.x;
    const float4* p4 = (const float4*)(pred + (size_t)blockIdx.x * (PB * 85));
    for (int i = t; i < PB * 85 / 4; i += PREP_TPB) s4[i] = p4[i];
    __syncthreads();
    if (t < PB) {
        const float* row = s + t * 85;
        float x = row[0], y = row[1], w = row[2], h = row[3], obj = row[4];
        float best = -INFINITY;
        #pragma unroll 8
        for (int c = 0; c < NC; ++c) {
            float v = __fmul_rn(row[5 + c], obj);
            if (v > best) best = v;          // strict >: first index on ties
        }
        float hw = __fmul_rn(w, 0.5f), hh = __fmul_rn(h, 0.5f);
        bool valid = (obj > 0.25f) && (best > 0.25f);
        int g = blockIdx.x * PB + t;
        sc[g]  = valid ? best : -INFINITY;
        box[g] = make_float4(__fsub_rn(x, hw), __fsub_rn(y, hh),
                             __fadd_rn(x, hw), __fadd_rn(y, hh));
    }
}

// ---------------------------------------------------------------------------
// NMS: one block per image, one block per CU (launch_bounds(512,2) -> 256
// VGPR budget). Hybrid storage sized to ACTUALLY fit registers (round-2 spill
// fix): slices 0..43 (22528 boxes) in VGPRs, slices 44..49 (2672 boxes) in
// LDS SoA (48 KB, per-lane stride 4B = conflict-free). All 50 score slices
// in VGPRs. Suppression is pure VALU + a few conflict-free ds_read_b32.
// Single barrier per iteration (parity-double-buffered leader slots).
// IoU test: fdiv_rn(inter,denom) > 0.45f  <=>  inter > K*denom exactly,
// K = (double)0.45f + 2^-26 (0.45f mantissa even => midpoint rounds down;
// 25-bit x 24-bit f64 product is exact), so selection is bit-identical.
// ---------------------------------------------------------------------------
#define TPB   512
#define EPT   50                 // 512*50 = 25600 >= 25200
#define EPTR  44                 // register-resident slices
#define NLDSS (EPT - EPTR)       // 6 LDS-resident slices
#define LDSN  (NLDSS * TPB)      // 3072 elements
#define NWAVE (TPB / 64)

__global__ __launch_bounds__(TPB, 2)
void nms_kernel(const float* __restrict__ sc_g,
                const float4* __restrict__ box_g,
                int* __restrict__ selidx,
                int* __restrict__ selcnt) {
    __shared__ float sx1[LDSN], sy1[LDSN], sx2[LDSN], sy2[LDSN];
    __shared__ float s_v[2][NWAVE];
    __shared__ int   s_i[2][NWAVE];
    const int img = blockIdx.x, t = threadIdx.x;
    const float*  sci = sc_g  + (size_t)img * NPRED;
    const float4* bxi = box_g + (size_t)img * NPRED;

    float sc[EPT];
    float x1[EPTR], y1[EPTR], x2[EPTR], y2[EPTR];
    #pragma unroll
    for (int i = 0; i < EPTR; ++i) {          // e <= 22527 < NPRED: no guard
        int e = t + i * TPB;
        sc[i] = sci[e];
        float4 b = bxi[e];
        x1[i] = b.x; y1[i] = b.y; x2[i] = b.z; y2[i] = b.w;
    }
    #pragma unroll
    for (int j = 0; j < NLDSS; ++j) {
        int i = EPTR + j;
        int e = t + i * TPB;
        int l = j * TPB + t;
        if (e < NPRED) {
            sc[i] = sci[e];
            float4 b = bxi[e];
            sx1[l] = b.x; sy1[l] = b.y; sx2[l] = b.z; sy2[l] = b.w;
        } else {
            sc[i] = -INFINITY;
            sx1[l] = 0.0f; sy1[l] = 0.0f; sx2[l] = 0.0f; sy2[l] = 0.0f;
        }
    }
    __syncthreads();

    const double K = (double)0.45f + 0x1p-26;

    int n = 0;
    for (int it = 0; it < MAXDET; ++it) {
        // local argmax (ascending e; strict > keeps first index on ties)
        float bv = -INFINITY; int bi = 0x7FFFFFFF;
        #pragma unroll
        for (int i = 0; i < EPT; ++i)
            if (sc[i] > bv) { bv = sc[i]; bi = t + i * TPB; }
        // wave reduce
        #pragma unroll
        for (int off = 32; off > 0; off >>= 1) {
            float ov = __shfl_down(bv, off);
            int   oi = __shfl_down(bi, off);
            if (ov > bv || (ov == bv && oi < bi)) { bv = ov; bi = oi; }
        }
        const int par = it & 1;
        if ((t & 63) == 0) { s_v[par][t >> 6] = bv; s_i[par][t >> 6] = bi; }
        __syncthreads();
        // every thread reduces the 8 leader pairs (broadcast LDS reads) —
        // result is uniform, so no second barrier and a uniform break.
        bv = s_v[par][0]; bi = s_i[par][0];
        #pragma unroll
        for (int w = 1; w < NWAVE; ++w) {
            float ov = s_v[par][w]; int oi = s_i[par][w];
            if (ov > bv || (ov == bv && oi < bi)) { bv = ov; bi = oi; }
        }
        if (bv == -INFINITY) break;
        if (t == 0) selidx[img * MAXDET + it] = bi;
        n = it + 1;

        float4 B = bxi[bi];   // lane-uniform broadcast load (L2)
        float barea = __fmul_rn(__fsub_rn(B.z, B.x), __fsub_rn(B.w, B.y));

        // suppression: register part (pure predicated VALU; selected box
        // self-suppresses via IoU~1, matching the reference's where())
        #pragma unroll
        for (int i = 0; i < EPTR; ++i) {
            float lx = fmaxf(B.x, x1[i]), ly = fmaxf(B.y, y1[i]);
            float rx = fminf(B.z, x2[i]), ry = fminf(B.w, y2[i]);
            float ww  = fmaxf(__fsub_rn(rx, lx), 0.0f);
            float hh2 = fmaxf(__fsub_rn(ry, ly), 0.0f);
            float inter = __fmul_rn(ww, hh2);
            float a = __fmul_rn(__fsub_rn(x2[i], x1[i]), __fsub_rn(y2[i], y1[i]));
            float denom = __fadd_rn(__fsub_rn(__fadd_rn(barea, a), inter), 1e-9f);
            if ((double)inter > K * (double)denom) sc[i] = -INFINITY;
        }
        // suppression: LDS part (conflict-free stride-4B reads)
        #pragma unroll
        for (int j = 0; j < NLDSS; ++j) {
            int i = EPTR + j;
            int l = j * TPB + t;
            float bx1 = sx1[l], by1 = sy1[l], bx2 = sx2[l], by2 = sy2[l];
            float lx = fmaxf(B.x, bx1), ly = fmaxf(B.y, by1);
            float rx = fminf(B.z, bx2), ry = fminf(B.w, by2);
            float ww  = fmaxf(__fsub_rn(rx, lx), 0.0f);
            float hh2 = fmaxf(__fsub_rn(ry, ly), 0.0f);
            float inter = __fmul_rn(ww, hh2);
            float a = __fmul_rn(__fsub_rn(bx2, bx1), __fsub_rn(by2, by1));
            float denom = __fadd_rn(__fsub_rn(__fadd_rn(barea, a), inter), 1e-9f);
            if ((double)inter > K * (double)denom) sc[i] = -INFINITY;
        }
    }
    if (t == 0) selcnt[img] = n;
}

// ---------------------------------------------------------------------------
// Gather: writes every output element (zeros for padding rows — no memset
// needed). conf/cls/obj recomputed from pred with the identical rn ops.
// ---------------------------------------------------------------------------
#define GT 256

__global__ __launch_bounds__(GT)
void gather_kernel(const float* __restrict__ pred,
                   const float4* __restrict__ box,
                   const float* __restrict__ logits,
                   const int* __restrict__ selidx,
                   const int* __restrict__ selcnt,
                   float* __restrict__ out) {
    int tid = blockIdx.x * GT + threadIdx.x;
    if (tid >= BATCH * MAXDET * NDIM) return;
    int row = tid / NDIM, col = tid - row * NDIM;
    int img = row / MAXDET, det = row - img * MAXDET;
    float v = 0.0f;
    if (det < selcnt[img]) {
        int s = selidx[img * MAXDET + det];
        size_t g = (size_t)img * NPRED + s;
        if (col < 4) {
            float4 b = box[g];
            v = (col == 0) ? b.x : (col == 1) ? b.y : (col == 2) ? b.z : b.w;
        } else if (col == 6) {
            v = pred[g * 85 + 4];
        } else if (col >= 7) {
            v = logits[g * NC + (col - 7)];
        } else {
            const float* p = pred + g * 85;
            float obj = p[4];
            float best = -INFINITY; int bc = 0;
            #pragma unroll 8
            for (int c = 0; c < NC; ++c) {
                float q = __fmul_rn(p[5 + c], obj);
                if (q > best) { best = q; bc = c; }
            }
            v = (col == 4) ? best : (float)bc;
        }
    }
    out[tid] = v;
}

extern "C" void kernel_launch(void* const* d_in, const int* in_sizes, int n_in,
                              void* d_out, int out_size, void* d_ws, size_t ws_size,
                              hipStream_t stream) {
    const float* pred   = (const float*)d_in[0];
    const float* logits = (const float*)d_in[1];
    float* out = (float*)d_out;

    char* ws = (char*)d_ws;
    float*  sc     = (float*)ws;                                   // 1,612,800 B
    float4* box    = (float4*)(ws + 1612800);                      // 6,451,200 B
    int*    selidx = (int*)(ws + 1612800 + 6451200);               //    19,200 B
    int*    selcnt = (int*)(ws + 1612800 + 6451200 + 19200);       //        64 B

    prep_kernel<<<BATCH * NPRED / PB, PREP_TPB, 0, stream>>>(pred, sc, box);
    nms_kernel<<<BATCH, TPB, 0, stream>>>(sc, box, selidx, selcnt);
    int gtot = BATCH * MAXDET * NDIM;
    gather_kernel<<<(gtot + GT - 1) / GT, GT, 0, stream>>>(pred, box, logits, selidx, selcnt, out);
}